// Round 2
// baseline (66.173 us; speedup 1.0000x reference)
//
#include <hip/hip_runtime.h>
#include <hip/hip_bf16.h>
#include <math.h>

// out[i,j] = max( (x[i]·W[j]) / (|x_i| |W_j|), 1e-10 ) + b[j]
// B=65536, IN=OUT=256, fp32 in/out.
// Round 2: 2 blocks/CU (each 256 rows x 128 cols, W-half 64KB LDS),
// swapped MFMA (A=W, B=x) -> float4 stores + in-lane x_len.

using bf16x8 = __attribute__((ext_vector_type(8))) short;   // 8 bf16 = 4 VGPRs
using f32x4  = __attribute__((ext_vector_type(4))) float;   // MFMA accumulator

#define W_LDS_BYTES 65536                     // 128 rows * 512 B (bf16, swizzled)
#define LDS_BYTES   (W_LDS_BYTES + 512 + 512) // + winv[128] + b[128]
#define EPS 1e-10f

__device__ __forceinline__ short f2bf(float f) {
    __bf16 h = (__bf16)f;                     // RNE; pairs fuse to v_cvt_pk_bf16_f32
    return __builtin_bit_cast(short, h);
}

__global__ __launch_bounds__(512, 4) void ffn_cosnorm_kernel(
    const float* __restrict__ x, const float* __restrict__ W,
    const float* __restrict__ b, float* __restrict__ out)
{
    extern __shared__ char smem[];
    float* winv = (float*)(smem + W_LDS_BYTES);          // [128] 1/|W_j|
    float* blds = (float*)(smem + W_LDS_BYTES + 512);    // [128] bias

    const int t     = threadIdx.x;
    const int rowgrp = blockIdx.x >> 1;      // 0..255 : which 256-row slab
    const int colh   = blockIdx.x & 1;       // 0/1    : which 128-col half
    const int colbase = colh * 128;

    // ---------------- prologue: stage W-half (fp32->bf16, XOR-swizzled) + w_len ----------------
    {
        const int wrow = t >> 2;             // 0..127 local W row (output col)
        const int q    = t & 3;              // 64-float quarter of the row
        const float* wr = W + (size_t)(colbase + wrow) * 256 + q * 64;
        const int rx = (wrow & 7) << 4;      // swizzle term
        float ss = 0.f;
        #pragma unroll
        for (int i = 0; i < 8; ++i) {        // 8 groups of 8 floats
            float4 a = *(const float4*)(wr + i * 8);
            float4 c = *(const float4*)(wr + i * 8 + 4);
            ss = fmaf(a.x, a.x, ss); ss = fmaf(a.y, a.y, ss);
            ss = fmaf(a.z, a.z, ss); ss = fmaf(a.w, a.w, ss);
            ss = fmaf(c.x, c.x, ss); ss = fmaf(c.y, c.y, ss);
            ss = fmaf(c.z, c.z, ss); ss = fmaf(c.w, c.w, ss);
            bf16x8 v;
            v[0] = f2bf(a.x); v[1] = f2bf(a.y); v[2] = f2bf(a.z); v[3] = f2bf(a.w);
            v[4] = f2bf(c.x); v[5] = f2bf(c.y); v[6] = f2bf(c.z); v[7] = f2bf(c.w);
            const int off = wrow * 512 + ((q * 128 + i * 16) ^ rx);
            *(bf16x8*)(smem + off) = v;      // ds_write_b128
        }
        ss += __shfl_xor(ss, 1);             // combine the 4 quarters (adjacent lanes)
        ss += __shfl_xor(ss, 2);
        if (q == 0) winv[wrow] = 1.0f / sqrtf(ss);
        if (t < 128) blds[t] = b[colbase + t];
    }
    __syncthreads();                         // only block-wide barrier

    // ---------------- main: each wave owns 32 rows (2 M-tiles), 128 cols ----------------
    const int lane = t & 63;
    const int wave = t >> 6;                 // 0..7
    const int r16  = lane & 15;              // x row within M-tile  (= D col)
    const int kg   = lane >> 4;              // 0..3 : K-slice of 8
    const int rxor = (r16 & 7) << 4;         // W-frag read swizzle
    const size_t rowBase = (size_t)rowgrp * 256 + (size_t)wave * 32;

    const float* xp0 = x + (rowBase + r16) * 256 + kg * 8;   // M-tile 0 row
    const float* xp1 = xp0 + 16 * 256;                        // M-tile 1 row

    f32x4 acc0[8], acc1[8];
    #pragma unroll
    for (int n = 0; n < 8; ++n) {
        acc0[n] = f32x4{0.f, 0.f, 0.f, 0.f};
        acc1[n] = f32x4{0.f, 0.f, 0.f, 0.f};
    }

    float ss0 = 0.f, ss1 = 0.f;

    float4 c0a = *(const float4*)(xp0);
    float4 c0b = *(const float4*)(xp0 + 4);
    float4 c1a = *(const float4*)(xp1);
    float4 c1b = *(const float4*)(xp1 + 4);

    #pragma unroll
    for (int k0 = 0; k0 < 8; ++k0) {         // K = 8 steps of 32
        float4 n0a, n0b, n1a, n1b;
        if (k0 < 7) {                        // depth-1 prefetch of next K-step
            const float* p0 = xp0 + (k0 + 1) * 32;
            n0a = *(const float4*)(p0);  n0b = *(const float4*)(p0 + 4);
            const float* p1 = xp1 + (k0 + 1) * 32;
            n1a = *(const float4*)(p1);  n1b = *(const float4*)(p1 + 4);
        }
        // convert current to bf16 frags + accumulate sum of squares (fp32)
        bf16x8 a0, a1;
        a0[0] = f2bf(c0a.x); a0[1] = f2bf(c0a.y); a0[2] = f2bf(c0a.z); a0[3] = f2bf(c0a.w);
        a0[4] = f2bf(c0b.x); a0[5] = f2bf(c0b.y); a0[6] = f2bf(c0b.z); a0[7] = f2bf(c0b.w);
        a1[0] = f2bf(c1a.x); a1[1] = f2bf(c1a.y); a1[2] = f2bf(c1a.z); a1[3] = f2bf(c1a.w);
        a1[4] = f2bf(c1b.x); a1[5] = f2bf(c1b.y); a1[6] = f2bf(c1b.z); a1[7] = f2bf(c1b.w);
        ss0 = fmaf(c0a.x, c0a.x, ss0); ss0 = fmaf(c0a.y, c0a.y, ss0);
        ss0 = fmaf(c0a.z, c0a.z, ss0); ss0 = fmaf(c0a.w, c0a.w, ss0);
        ss0 = fmaf(c0b.x, c0b.x, ss0); ss0 = fmaf(c0b.y, c0b.y, ss0);
        ss0 = fmaf(c0b.z, c0b.z, ss0); ss0 = fmaf(c0b.w, c0b.w, ss0);
        ss1 = fmaf(c1a.x, c1a.x, ss1); ss1 = fmaf(c1a.y, c1a.y, ss1);
        ss1 = fmaf(c1a.z, c1a.z, ss1); ss1 = fmaf(c1a.w, c1a.w, ss1);
        ss1 = fmaf(c1b.x, c1b.x, ss1); ss1 = fmaf(c1b.y, c1b.y, ss1);
        ss1 = fmaf(c1b.z, c1b.z, ss1); ss1 = fmaf(c1b.w, c1b.w, ss1);

        const int cswz = (k0 * 64 + kg * 16) ^ rxor;   // swizzled byte-col in W row
        #pragma unroll
        for (int n = 0; n < 8; ++n) {
            const int addr = (n * 16 + r16) * 512 + cswz;
            bf16x8 wfr = *(const bf16x8*)(smem + addr);  // ds_read_b128
            // SWAPPED: D[j][m] = sum_k W[j][k] x[m][k]  -> lane holds 4 consecutive cols j
            acc0[n] = __builtin_amdgcn_mfma_f32_16x16x32_bf16(wfr, a0, acc0[n], 0, 0, 0);
            acc1[n] = __builtin_amdgcn_mfma_f32_16x16x32_bf16(wfr, a1, acc1[n], 0, 0, 0);
        }
        c0a = n0a; c0b = n0b; c1a = n1a; c1b = n1b;
    }

    // ---------------- x_len: butterfly over K-groups; result is already in-lane ----------------
    ss0 += __shfl_xor(ss0, 16); ss0 += __shfl_xor(ss0, 32);   // full sumsq of row r16
    ss1 += __shfl_xor(ss1, 16); ss1 += __shfl_xor(ss1, 32);
    const float inv0 = 1.0f / sqrtf(ss0);    // D col (=x row) is lane&15 -> no broadcast needed
    const float inv1 = 1.0f / sqrtf(ss1);

    // ---------------- epilogue: scale, clamp, +bias, float4 stores ----------------
    const int jb = kg * 4;                   // col offset within 16-tile
    float* op0 = out + (rowBase + r16) * 256 + colbase;
    float* op1 = op0 + (size_t)16 * 256;
    #pragma unroll
    for (int n = 0; n < 8; ++n) {
        float4 wv = *(const float4*)(winv + n * 16 + jb);
        float4 bv = *(const float4*)(blds + n * 16 + jb);
        float4 o0, o1;
        o0.x = fmaxf(acc0[n][0] * (inv0 * wv.x), EPS) + bv.x;
        o0.y = fmaxf(acc0[n][1] * (inv0 * wv.y), EPS) + bv.y;
        o0.z = fmaxf(acc0[n][2] * (inv0 * wv.z), EPS) + bv.z;
        o0.w = fmaxf(acc0[n][3] * (inv0 * wv.w), EPS) + bv.w;
        o1.x = fmaxf(acc1[n][0] * (inv1 * wv.x), EPS) + bv.x;
        o1.y = fmaxf(acc1[n][1] * (inv1 * wv.y), EPS) + bv.y;
        o1.z = fmaxf(acc1[n][2] * (inv1 * wv.z), EPS) + bv.z;
        o1.w = fmaxf(acc1[n][3] * (inv1 * wv.w), EPS) + bv.w;
        *(float4*)(op0 + n * 16 + jb) = o0;  // global_store_dwordx4, 64B runs per row
        *(float4*)(op1 + n * 16 + jb) = o1;
    }
}

extern "C" void kernel_launch(void* const* d_in, const int* in_sizes, int n_in,
                              void* d_out, int out_size, void* d_ws, size_t ws_size,
                              hipStream_t stream) {
    const float* x = (const float*)d_in[0];
    const float* W = (const float*)d_in[1];
    const float* b = (const float*)d_in[2];
    float* out = (float*)d_out;

    hipFuncSetAttribute((const void*)ffn_cosnorm_kernel,
                        hipFuncAttributeMaxDynamicSharedMemorySize, LDS_BYTES);
    ffn_cosnorm_kernel<<<dim3(512), dim3(512), LDS_BYTES, stream>>>(x, W, b, out);
}

// Round 3
// 51.942 us; speedup vs baseline: 1.2740x; 1.2740x over previous
//
#include <hip/hip_runtime.h>
#include <hip/hip_bf16.h>
#include <math.h>

// out[i,j] = max( (x[i]·W[j]) / (|x_i| |W_j|), 1e-10 ) + b[j]
// B=65536, IN=OUT=256, fp32 in/out.
// Round 3: 1024-thread blocks (16 waves x 16 rows), full W bf16 in LDS (swizzled),
// swapped MFMA (A=W, B=x) -> in-lane x_len + contiguous float4 nontemporal stores.

using bf16x8 = __attribute__((ext_vector_type(8))) short;   // 8 bf16 = 4 VGPRs
using f32x4  = __attribute__((ext_vector_type(4))) float;   // MFMA accumulator / NT store

#define W_LDS_BYTES 131072                        // 256 rows * 512 B (bf16, swizzled)
#define LDS_BYTES   (W_LDS_BYTES + 1024 + 1024)   // + winv[256] + b[256]
#define EPS 1e-10f

__device__ __forceinline__ short f2bf(float f) {
    __bf16 h = (__bf16)f;                         // RNE; pairs fuse to v_cvt_pk_bf16_f32
    return __builtin_bit_cast(short, h);
}

__global__ __launch_bounds__(1024, 4) void ffn_cosnorm_kernel(
    const float* __restrict__ x, const float* __restrict__ W,
    const float* __restrict__ b, float* __restrict__ out)
{
    extern __shared__ char smem[];
    float* winv = (float*)(smem + W_LDS_BYTES);           // [256] 1/|W_j|
    float* blds = (float*)(smem + W_LDS_BYTES + 1024);    // [256] bias

    const int t = threadIdx.x;

    // ---------------- prologue: stage W (fp32->bf16, XOR-swizzled) + w_len ----------------
    {
        const int wrow = t >> 2;              // 0..255 W row (output col j)
        const int q    = t & 3;               // 64-float quarter of the row
        const float* wr = W + (size_t)wrow * 256 + q * 64;
        const int rx = (wrow & 7) << 4;       // swizzle term
        float ss = 0.f;
        #pragma unroll
        for (int i = 0; i < 8; ++i) {         // 8 groups of 8 floats
            float4 a = *(const float4*)(wr + i * 8);
            float4 c = *(const float4*)(wr + i * 8 + 4);
            ss = fmaf(a.x, a.x, ss); ss = fmaf(a.y, a.y, ss);
            ss = fmaf(a.z, a.z, ss); ss = fmaf(a.w, a.w, ss);
            ss = fmaf(c.x, c.x, ss); ss = fmaf(c.y, c.y, ss);
            ss = fmaf(c.z, c.z, ss); ss = fmaf(c.w, c.w, ss);
            bf16x8 v;
            v[0] = f2bf(a.x); v[1] = f2bf(a.y); v[2] = f2bf(a.z); v[3] = f2bf(a.w);
            v[4] = f2bf(c.x); v[5] = f2bf(c.y); v[6] = f2bf(c.z); v[7] = f2bf(c.w);
            const int off = wrow * 512 + ((q * 128 + i * 16) ^ rx);
            *(bf16x8*)(smem + off) = v;       // ds_write_b128
        }
        ss += __shfl_xor(ss, 1);              // combine the 4 quarters (adjacent lanes)
        ss += __shfl_xor(ss, 2);
        if (q == 0) winv[wrow] = 1.0f / sqrtf(ss);
        if (t < 256) blds[t] = b[t];
    }
    __syncthreads();                          // only block-wide barrier

    // ---------------- main: each wave owns ONE 16-row M-tile, all 256 cols ----------------
    const int lane = t & 63;
    const int wave = t >> 6;                  // 0..15
    const int r16  = lane & 15;               // x row within M-tile (= D col, in-lane)
    const int kg   = lane >> 4;               // 0..3 : K-slice of 8
    const int rxor = (r16 & 15) ? ((r16 & 7) << 4) : 0;  // = (r16&7)<<4
    const size_t row = (size_t)blockIdx.x * 256 + (size_t)wave * 16 + r16;

    const float* xp = x + row * 256 + kg * 8;

    f32x4 acc[16];
    #pragma unroll
    for (int n = 0; n < 16; ++n) acc[n] = f32x4{0.f, 0.f, 0.f, 0.f};

    float ssx = 0.f;

    float4 ca = *(const float4*)(xp);
    float4 cb = *(const float4*)(xp + 4);

    #pragma unroll
    for (int k0 = 0; k0 < 8; ++k0) {          // K = 8 steps of 32
        float4 na, nb;
        if (k0 < 7) {                         // depth-1 prefetch of next K-step
            const float* p = xp + (k0 + 1) * 32;
            na = *(const float4*)(p);  nb = *(const float4*)(p + 4);
        }
        // convert current to bf16 frag + accumulate sum of squares (fp32)
        bf16x8 a0;
        a0[0] = f2bf(ca.x); a0[1] = f2bf(ca.y); a0[2] = f2bf(ca.z); a0[3] = f2bf(ca.w);
        a0[4] = f2bf(cb.x); a0[5] = f2bf(cb.y); a0[6] = f2bf(cb.z); a0[7] = f2bf(cb.w);
        ssx = fmaf(ca.x, ca.x, ssx); ssx = fmaf(ca.y, ca.y, ssx);
        ssx = fmaf(ca.z, ca.z, ssx); ssx = fmaf(ca.w, ca.w, ssx);
        ssx = fmaf(cb.x, cb.x, ssx); ssx = fmaf(cb.y, cb.y, ssx);
        ssx = fmaf(cb.z, cb.z, ssx); ssx = fmaf(cb.w, cb.w, ssx);

        const int cswz = (k0 * 64 + kg * 16) ^ rxor;   // swizzled byte-col in W row
        #pragma unroll
        for (int n = 0; n < 16; ++n) {
            const int addr = (n * 16 + r16) * 512 + cswz;
            bf16x8 wfr = *(const bf16x8*)(smem + addr);  // ds_read_b128
            // SWAPPED: D[j][m] = sum_k W[j][k] x[m][k] -> lane holds 4 consecutive cols j
            acc[n] = __builtin_amdgcn_mfma_f32_16x16x32_bf16(wfr, a0, acc[n], 0, 0, 0);
        }
        ca = na; cb = nb;
    }

    // ---------------- x_len: butterfly over K-groups; result already in-lane ----------------
    ssx += __shfl_xor(ssx, 16); ssx += __shfl_xor(ssx, 32);   // full sumsq of row r16
    const float inv = 1.0f / sqrtf(ssx);      // D col (= x row) is lane&15 -> no broadcast

    // ---------------- epilogue: scale, clamp, +bias, nontemporal float4 stores ----------------
    const int jb = kg * 4;                    // col offset within 16-tile
    float* op = out + row * 256;
    #pragma unroll
    for (int n = 0; n < 16; ++n) {
        float4 wv = *(const float4*)(winv + n * 16 + jb);
        float4 bv = *(const float4*)(blds + n * 16 + jb);
        f32x4 o;
        o[0] = fmaxf(acc[n][0] * (inv * wv.x), EPS) + bv.x;
        o[1] = fmaxf(acc[n][1] * (inv * wv.y), EPS) + bv.y;
        o[2] = fmaxf(acc[n][2] * (inv * wv.z), EPS) + bv.z;
        o[3] = fmaxf(acc[n][3] * (inv * wv.w), EPS) + bv.w;
        __builtin_nontemporal_store(o, (f32x4*)(op + n * 16 + jb));  // full 1KB rows per wave
    }
}

extern "C" void kernel_launch(void* const* d_in, const int* in_sizes, int n_in,
                              void* d_out, int out_size, void* d_ws, size_t ws_size,
                              hipStream_t stream) {
    const float* x = (const float*)d_in[0];
    const float* W = (const float*)d_in[1];
    const float* b = (const float*)d_in[2];
    float* out = (float*)d_out;

    hipFuncSetAttribute((const void*)ffn_cosnorm_kernel,
                        hipFuncAttributeMaxDynamicSharedMemorySize, LDS_BYTES);
    ffn_cosnorm_kernel<<<dim3(256), dim3(1024), LDS_BYTES, stream>>>(x, W, b, out);
}

// Round 4
// 46.033 us; speedup vs baseline: 1.4375x; 1.1284x over previous
//
#include <hip/hip_runtime.h>
#include <hip/hip_bf16.h>
#include <math.h>

// out[i,j] = max( (x[i]·W[j]) / (|x_i| |W_j|), 1e-10 ) + b[j]
// B=65536, IN=OUT=256, fp32 in/out.
// Round 4: R3 structure + (a) depth-2 ring prefetch of x pre-issued before the
// W prologue, (b) epilogue LDS-transpose so every global store is a full
// contiguous 512B run (4 full 128B lines) -> nontemporal safe, no write
// amplification. W-LDS region is reused as the store-staging buffer.

using bf16x8 = __attribute__((ext_vector_type(8))) short;   // 8 bf16 = 4 VGPRs
using f32x4  = __attribute__((ext_vector_type(4))) float;

#define W_LDS_BYTES 131072                        // 256 rows * 512 B (bf16, swizzled)
#define LDS_BYTES   (W_LDS_BYTES + 1024 + 1024)   // + winv[256] + b[256]
#define EPS 1e-10f

__device__ __forceinline__ short f2bf(float f) {
    __bf16 h = (__bf16)f;                         // RNE; pairs fuse to v_cvt_pk_bf16_f32
    return __builtin_bit_cast(short, h);
}

__global__ __launch_bounds__(1024, 4) void ffn_cosnorm_kernel(
    const float* __restrict__ x, const float* __restrict__ W,
    const float* __restrict__ b, float* __restrict__ out)
{
    extern __shared__ char smem[];
    float* winv = (float*)(smem + W_LDS_BYTES);           // [256] 1/|W_j|
    float* blds = (float*)(smem + W_LDS_BYTES + 1024);    // [256] bias

    const int t    = threadIdx.x;
    const int lane = t & 63;
    const int wave = t >> 6;                  // 0..15
    const int r16  = lane & 15;               // x row within wave's 16-row tile
    const int kg   = lane >> 4;               // 0..3 : K-slice of 8
    const int r7   = r16 & 7;
    const size_t rowb = (size_t)blockIdx.x * 256 + (size_t)wave * 16;
    const float* xp = x + (rowb + r16) * 256 + kg * 8;

    // ---- pre-issue first two x K-steps: they land during the W prologue ----
    float4 ra[2], rb[2];
    ra[0] = *(const float4*)(xp);       rb[0] = *(const float4*)(xp + 4);
    ra[1] = *(const float4*)(xp + 32);  rb[1] = *(const float4*)(xp + 36);

    // ---------------- prologue: stage W (fp32->bf16, XOR-swizzled) + w_len ----------------
    {
        const int wrow = t >> 2;              // 0..255 W row (output col j)
        const int q    = t & 3;               // 64-float quarter of the row
        const float* wr = W + (size_t)wrow * 256 + q * 64;
        const int rx = (wrow & 7) << 4;       // swizzle term
        float ss = 0.f;
        #pragma unroll
        for (int i = 0; i < 8; ++i) {         // 8 groups of 8 floats
            float4 a = *(const float4*)(wr + i * 8);
            float4 c = *(const float4*)(wr + i * 8 + 4);
            ss = fmaf(a.x, a.x, ss); ss = fmaf(a.y, a.y, ss);
            ss = fmaf(a.z, a.z, ss); ss = fmaf(a.w, a.w, ss);
            ss = fmaf(c.x, c.x, ss); ss = fmaf(c.y, c.y, ss);
            ss = fmaf(c.z, c.z, ss); ss = fmaf(c.w, c.w, ss);
            bf16x8 v;
            v[0] = f2bf(a.x); v[1] = f2bf(a.y); v[2] = f2bf(a.z); v[3] = f2bf(a.w);
            v[4] = f2bf(c.x); v[5] = f2bf(c.y); v[6] = f2bf(c.z); v[7] = f2bf(c.w);
            const int off = wrow * 512 + ((q * 128 + i * 16) ^ rx);
            *(bf16x8*)(smem + off) = v;       // ds_write_b128
        }
        ss += __shfl_xor(ss, 1);              // combine the 4 quarters
        ss += __shfl_xor(ss, 2);
        if (q == 0) winv[wrow] = 1.0f / sqrtf(ss);
        if (t < 256) blds[t] = b[t];
    }
    __syncthreads();

    // ---------------- main: each wave one 16-row M-tile, all 256 cols ----------------
    const int rxor = r7 << 4;                 // W-frag read swizzle

    f32x4 acc[16];
    #pragma unroll
    for (int n = 0; n < 16; ++n) acc[n] = f32x4{0.f, 0.f, 0.f, 0.f};
    float ssx = 0.f;

    #pragma unroll
    for (int k0 = 0; k0 < 8; ++k0) {          // K = 8 steps of 32
        const int slot = k0 & 1;              // static after unroll
        float4 ca = ra[slot], cb = rb[slot];
        if (k0 < 6) {                         // ring refill: 2 K-steps ahead
            const float* p = xp + (k0 + 2) * 32;
            ra[slot] = *(const float4*)(p);
            rb[slot] = *(const float4*)(p + 4);
        }
        bf16x8 a0;
        a0[0] = f2bf(ca.x); a0[1] = f2bf(ca.y); a0[2] = f2bf(ca.z); a0[3] = f2bf(ca.w);
        a0[4] = f2bf(cb.x); a0[5] = f2bf(cb.y); a0[6] = f2bf(cb.z); a0[7] = f2bf(cb.w);
        ssx = fmaf(ca.x, ca.x, ssx); ssx = fmaf(ca.y, ca.y, ssx);
        ssx = fmaf(ca.z, ca.z, ssx); ssx = fmaf(ca.w, ca.w, ssx);
        ssx = fmaf(cb.x, cb.x, ssx); ssx = fmaf(cb.y, cb.y, ssx);
        ssx = fmaf(cb.z, cb.z, ssx); ssx = fmaf(cb.w, cb.w, ssx);

        const int cswz = (k0 * 64 + kg * 16) ^ rxor;
        #pragma unroll
        for (int n = 0; n < 16; ++n) {
            const int addr = (n * 16 + r16) * 512 + cswz;
            bf16x8 wfr = *(const bf16x8*)(smem + addr);   // ds_read_b128
            // SWAPPED: D[j][m] -> lane holds 4 consecutive cols j of row r16
            acc[n] = __builtin_amdgcn_mfma_f32_16x16x32_bf16(wfr, a0, acc[n], 0, 0, 0);
        }
    }

    // ---------------- x_len: butterfly over K-groups; in-lane result ----------------
    ssx += __shfl_xor(ssx, 16); ssx += __shfl_xor(ssx, 32);
    const float inv = 1.0f / sqrtf(ssx);      // 1/|x_row(r16)|

    // ---------------- epilogue: LDS-transpose -> full-line NT stores ----------------
    __syncthreads();                          // all waves done reading W; reuse as staging
    char* wbuf = smem + wave * 8192;          // 16 rows x 512 B (one 128-col half)
    const int halfsel = lane >> 5;            // 0/1
    const int l31 = lane & 31;

    #pragma unroll
    for (int h = 0; h < 2; ++h) {             // column half: cols h*128 .. h*128+127
        // stage: lane (r16, kg) writes its 8 n-windows of this half, swizzled
        #pragma unroll
        for (int n8 = 0; n8 < 8; ++n8) {
            const int n = h * 8 + n8;
            float4 wv = *(const float4*)(winv + n * 16 + kg * 4);
            float4 bv = *(const float4*)(blds + n * 16 + kg * 4);
            f32x4 o;
            o[0] = fmaxf(acc[n][0] * (inv * wv.x), EPS) + bv.x;
            o[1] = fmaxf(acc[n][1] * (inv * wv.y), EPS) + bv.y;
            o[2] = fmaxf(acc[n][2] * (inv * wv.z), EPS) + bv.z;
            o[3] = fmaxf(acc[n][3] * (inv * wv.w), EPS) + bv.w;
            const int off = r16 * 512 + ((n8 * 64 + kg * 16) ^ (r7 << 4));
            *(f32x4*)(wbuf + off) = o;        // ds_write_b128
        }
        // read back 2 rows per instruction (512 B each) and NT-store full runs
        #pragma unroll
        for (int rp = 0; rp < 8; ++rp) {
            const int rloc = rp * 2 + halfsel;            // local row 0..15
            f32x4 v = *(const f32x4*)(wbuf + rloc * 512 + l31 * 16);
            const int c = l31 ^ (rloc & 7);               // undo write swizzle
            float* dst = out + (rowb + rloc) * 256 + h * 128 + c * 4;
            __builtin_nontemporal_store(v, (f32x4*)dst);  // 512B contiguous per instr
        }
        // WAR fence: next h's ds_writes must not pass this h's ds_reads
        asm volatile("s_waitcnt lgkmcnt(0)" ::: "memory");
    }
}

extern "C" void kernel_launch(void* const* d_in, const int* in_sizes, int n_in,
                              void* d_out, int out_size, void* d_ws, size_t ws_size,
                              hipStream_t stream) {
    const float* x = (const float*)d_in[0];
    const float* W = (const float*)d_in[1];
    const float* b = (const float*)d_in[2];
    float* out = (float*)d_out;

    hipFuncSetAttribute((const void*)ffn_cosnorm_kernel,
                        hipFuncAttributeMaxDynamicSharedMemorySize, LDS_BYTES);
    ffn_cosnorm_kernel<<<dim3(256), dim3(1024), LDS_BYTES, stream>>>(x, W, b, out);
}